// Round 1
// baseline (642.443 us; speedup 1.0000x reference)
//
#include <hip/hip_runtime.h>
#include <cstdint>
#include <cstddef>

// Problem constants: B=1, S=2048, H=4096, NH=32, NKV=8, D=128, GQA group=4
#define S_LEN 2048
#define HID   4096
#define NHEAD 32
#define NKVH  8
#define HD    128

typedef __bf16 bf16x8 __attribute__((ext_vector_type(8)));
typedef float  f32x4  __attribute__((ext_vector_type(4)));

__device__ __forceinline__ unsigned short f2bf(float f) {
  union { float f; unsigned int u; } c; c.f = f;
  unsigned int u = c.u;
  return (unsigned short)((u + 0x7fffu + ((u >> 16) & 1u)) >> 16);  // RNE
}
__device__ __forceinline__ float bf2f(unsigned short b) {
  union { unsigned int u; float f; } c; c.u = ((unsigned int)b) << 16;
  return c.f;
}
__device__ __forceinline__ void gload16(const void* g, void* l) {
  __builtin_amdgcn_global_load_lds((const __attribute__((address_space(1))) void*)g,
                                   (__attribute__((address_space(3))) void*)l, 16, 0, 0);
}

// ---------------------------------------------------------------- fp32 -> bf16
__global__ void cvt_f32_bf16(const float* __restrict__ in,
                             unsigned short* __restrict__ out, int n4) {
  int i = blockIdx.x * blockDim.x + threadIdx.x;
  int stride = gridDim.x * blockDim.x;
  for (; i < n4; i += stride) {
    float4 v = ((const float4*)in)[i];
    ushort4 o;
    o.x = f2bf(v.x); o.y = f2bf(v.y); o.z = f2bf(v.z); o.w = f2bf(v.w);
    ((ushort4*)out)[i] = o;
  }
}

// ------------------------------------------------- C[M,N] = A[M,K] * B[N,K]^T
// m97 structure: 128x128 tile, BK=32, 4 waves, 4x4 16x16x32 mfma per wave.
template <bool F32OUT>
__global__ __launch_bounds__(256)
void gemm_bt(const unsigned short* __restrict__ A,
             const unsigned short* __restrict__ Bm,
             void* __restrict__ Cout, int M, int N, int K) {
  __shared__ __align__(16) unsigned short lA[128 * 32];
  __shared__ __align__(16) unsigned short lB[128 * 32];
  const int tid = threadIdx.x;
  const int lane = tid & 63, wid = tid >> 6;
  const int l15 = lane & 15, lg = lane >> 4;
  const int wr = (wid >> 1) * 64, wc = (wid & 1) * 64;
  const int bm = blockIdx.y, bn = blockIdx.x;
  f32x4 acc[4][4] = {};
  const unsigned short* Ab = A + (size_t)bm * 128 * K;
  const unsigned short* Bb = Bm + (size_t)bn * 128 * K;

  for (int k0 = 0; k0 < K; k0 += 32) {
#pragma unroll
    for (int i = 0; i < 2; ++i) {     // 512 16B chunks per 8KB tile, 2/thread
      int c = tid + i * 256;
      int row = c >> 2, sl = c & 3;
      gload16(Ab + (size_t)row * K + k0 + sl * 8, (char*)lA + c * 16);
      gload16(Bb + (size_t)row * K + k0 + sl * 8, (char*)lB + c * 16);
    }
    __syncthreads();                  // drains vmcnt -> tiles staged
    bf16x8 af[4], bfr[4];
#pragma unroll
    for (int m = 0; m < 4; ++m)
      af[m] = *(const bf16x8*)&lA[(wr + m * 16 + l15) * 32 + lg * 8];
#pragma unroll
    for (int n = 0; n < 4; ++n)
      bfr[n] = *(const bf16x8*)&lB[(wc + n * 16 + l15) * 32 + lg * 8];
#pragma unroll
    for (int m = 0; m < 4; ++m)
#pragma unroll
      for (int n = 0; n < 4; ++n)
        acc[m][n] = __builtin_amdgcn_mfma_f32_16x16x32_bf16(af[m], bfr[n], acc[m][n], 0, 0, 0);
    __syncthreads();                  // protect LDS before next stage
  }
  // epilogue: C layout col=lane&15, row=4*(lane>>4)+reg
  const int r0 = bm * 128 + wr + 4 * lg;
  const int c0 = bn * 128 + wc + l15;
#pragma unroll
  for (int m = 0; m < 4; ++m)
#pragma unroll
    for (int n = 0; n < 4; ++n)
#pragma unroll
      for (int j = 0; j < 4; ++j) {
        size_t idx = (size_t)(r0 + m * 16 + j) * N + (c0 + n * 16);
        if (F32OUT) ((float*)Cout)[idx] = acc[m][n][j];
        else        ((unsigned short*)Cout)[idx] = f2bf(acc[m][n][j]);
      }
}

// ------------------------------------------------------------- RoPE, in place
// X: [S][nheads*128] bf16; cos/sin: [S][128] fp32 (cos[d]==cos[d+64])
__global__ void rope_kernel(unsigned short* __restrict__ X,
                            const float* __restrict__ cp,
                            const float* __restrict__ sp, int lognh) {
  int idx = blockIdx.x * blockDim.x + threadIdx.x;
  int d = idx & 63;
  int head = (idx >> 6) & ((1 << lognh) - 1);
  int s = idx >> (6 + lognh);
  float c = cp[s * 128 + d], sn = sp[s * 128 + d];
  size_t base = ((size_t)s << (lognh + 7)) + (head << 7) + d;
  float x1 = bf2f(X[base]), x2 = bf2f(X[base + 64]);
  X[base]      = f2bf(x1 * c - x2 * sn);
  X[base + 64] = f2bf(x2 * c + x1 * sn);
}

// ------------------------------------------------------------ flash attention
// grid: (S/64 q-tiles, NH heads); 256 threads = 4 waves, 16 q-rows per wave.
// K: LDS [64][128] with chunk-XOR swizzle (source-pre-swizzled global_load_lds)
// V: LDS transposed [128][64] with (d^(d>>3))&7 swizzle, register-staged
// P: per-wave LDS [16][64], (q&7) swizzle, C-layout -> A-frag layout round-trip
__global__ __launch_bounds__(256)
void flash_attn(const unsigned short* __restrict__ Q,
                const unsigned short* __restrict__ Kg,
                const unsigned short* __restrict__ Vg,
                unsigned short* __restrict__ Og) {
  __shared__ __align__(16) unsigned short lK[64 * 128];
  __shared__ __align__(16) unsigned short lVt[128 * 64];
  __shared__ __align__(16) unsigned short lP[4][16 * 64];
  const int tid = threadIdx.x;
  const int lane = tid & 63, wid = tid >> 6;
  const int l15 = lane & 15, lg = lane >> 4;
  const int h = blockIdx.y, qt = blockIdx.x;
  const int kvh = h >> 2;
  const int q0 = qt * 64 + wid * 16;
  const float SCALE = 0.08838834764831845f;  // 1/sqrt(128)

  // Q fragments, hoisted: row q0+l15, k = 8*lg + j within each 32-slice
  bf16x8 qf[4];
  {
    const unsigned short* qp = Q + (size_t)(q0 + l15) * (NHEAD * HD) + h * HD + lg * 8;
#pragma unroll
    for (int sl = 0; sl < 4; ++sl) qf[sl] = *(const bf16x8*)(qp + sl * 32);
  }
  float m_r[4], l_r[4];
  f32x4 accO[8] = {};
#pragma unroll
  for (int r = 0; r < 4; ++r) { m_r[r] = -1e30f; l_r[r] = 0.f; }
  unsigned short* lPw = lP[wid];

  for (int kt = 0; kt <= qt; ++kt) {
    __syncthreads();  // all waves done reading previous lK/lVt
    {   // stage K: 1024 chunks of 16B, swizzled global source
      const unsigned short* Kb = Kg + (size_t)(kt * 64) * (NKVH * HD) + kvh * HD;
#pragma unroll
      for (int i = 0; i < 4; ++i) {
        int c = tid + i * 256;
        int row = c >> 4, s = c & 15;
        int g = s ^ (row & 7);
        gload16(Kb + (size_t)row * (NKVH * HD) + g * 8, (char*)lK + c * 16);
      }
    }
    {   // stage V transposed via registers
      const unsigned short* Vb = Vg + (size_t)(kt * 64) * (NKVH * HD) + kvh * HD;
#pragma unroll
      for (int i = 0; i < 4; ++i) {
        int c = tid + i * 256;
        int row = c >> 4, s = c & 15;
        uint4 raw = *(const uint4*)(Vb + (size_t)row * (NKVH * HD) + s * 8);
        const unsigned short* pv = (const unsigned short*)&raw;
#pragma unroll
        for (int j = 0; j < 8; ++j) {
          int d = s * 8 + j;
          lVt[d * 64 + (row ^ (((d ^ (d >> 3)) & 7) << 3))] = pv[j];
        }
      }
    }
    __syncthreads();  // vmcnt+lgkm drained: K & V staged

    // QK^T: S[16 q x 64 kv], C layout: kv=lane&15 (+16*nb), q=4*lg+reg
    f32x4 sacc[4] = {};
#pragma unroll
    for (int sl = 0; sl < 4; ++sl)
#pragma unroll
      for (int nb = 0; nb < 4; ++nb) {
        int row = nb * 16 + l15;
        bf16x8 kf = *(const bf16x8*)&lK[row * 128 + (((sl * 4 + lg) ^ (row & 7)) * 8)];
        sacc[nb] = __builtin_amdgcn_mfma_f32_16x16x32_bf16(qf[sl], kf, sacc[nb], 0, 0, 0);
      }
    // scale + causal mask (diagonal tile only)
    const bool diag = (kt == qt);
#pragma unroll
    for (int nb = 0; nb < 4; ++nb)
#pragma unroll
      for (int r = 0; r < 4; ++r) {
        float sv = sacc[nb][r] * SCALE;
        if (diag && (nb * 16 + l15) > (wid * 16 + 4 * lg + r)) sv = -1e30f;
        sacc[nb][r] = sv;
      }
    // online softmax, rows owned per (lg, reg), 16-lane shfl reduce
#pragma unroll
    for (int r = 0; r < 4; ++r) {
      float mx = fmaxf(fmaxf(sacc[0][r], sacc[1][r]), fmaxf(sacc[2][r], sacc[3][r]));
#pragma unroll
      for (int off = 1; off < 16; off <<= 1) mx = fmaxf(mx, __shfl_xor(mx, off));
      float mnew = fmaxf(m_r[r], mx);
      float corr = __expf(m_r[r] - mnew);
      m_r[r] = mnew;
      float rsum = 0.f;
      int q = 4 * lg + r;
#pragma unroll
      for (int nb = 0; nb < 4; ++nb) {
        float p = __expf(sacc[nb][r] - mnew);
        rsum += p;
        int kv = nb * 16 + l15;
        lPw[q * 64 + (kv ^ ((q & 7) << 3))] = f2bf(p);
      }
#pragma unroll
      for (int off = 1; off < 16; off <<= 1) rsum += __shfl_xor(rsum, off);
      l_r[r] = l_r[r] * corr + rsum;
#pragma unroll
      for (int nd = 0; nd < 8; ++nd) accO[nd][r] *= corr;
    }
    // PV: O[16 x 128] += P[16 x 64] * V[64 x 128]
#pragma unroll
    for (int sl = 0; sl < 2; ++sl) {
      bf16x8 pf = *(const bf16x8*)&lPw[l15 * 64 + ((sl * 32 + lg * 8) ^ ((l15 & 7) << 3))];
#pragma unroll
      for (int nd = 0; nd < 8; ++nd) {
        int d = nd * 16 + l15;
        bf16x8 vf = *(const bf16x8*)&lVt[d * 64 + ((sl * 32 + lg * 8) ^ (((d ^ (d >> 3)) & 7) << 3))];
        accO[nd] = __builtin_amdgcn_mfma_f32_16x16x32_bf16(pf, vf, accO[nd], 0, 0, 0);
      }
    }
  }
  // epilogue: O /= l, write bf16 [s][h*128+d]
#pragma unroll
  for (int r = 0; r < 4; ++r) {
    float inv = 1.0f / l_r[r];
    size_t row = (size_t)(q0 + 4 * lg + r);
#pragma unroll
    for (int nd = 0; nd < 8; ++nd)
      Og[row * (NHEAD * HD) + h * HD + nd * 16 + l15] = f2bf(accO[nd][r] * inv);
  }
}

// ---------------------------------------------------------------------- launch
extern "C" void kernel_launch(void* const* d_in, const int* in_sizes, int n_in,
                              void* d_out, int out_size, void* d_ws, size_t ws_size,
                              hipStream_t stream) {
  const float* hs   = (const float*)d_in[0];
  const float* cosp = (const float*)d_in[1];
  const float* sinp = (const float*)d_in[2];
  // d_in[3] attention_mask: pure causal, implemented directly
  const float* Wq = (const float*)d_in[4];
  const float* Wk = (const float*)d_in[5];
  const float* Wv = (const float*)d_in[6];
  const float* Wo = (const float*)d_in[7];
  float* out = (float*)d_out;

  uint8_t* ws = (uint8_t*)d_ws;
  size_t off = 0;
  auto alloc = [&](size_t bytes) { void* p = ws + off; off += bytes; return p; };
  unsigned short* hidB = (unsigned short*)alloc((size_t)S_LEN * HID * 2);         // 16 MB
  unsigned short* wqB  = (unsigned short*)alloc((size_t)NHEAD * HD * HID * 2);    // 32 MB
  unsigned short* wkB  = (unsigned short*)alloc((size_t)NKVH * HD * HID * 2);     // 8 MB
  unsigned short* wvB  = (unsigned short*)alloc((size_t)NKVH * HD * HID * 2);     // 8 MB
  unsigned short* woB  = (unsigned short*)alloc((size_t)NHEAD * HD * NHEAD * HD * 2); // 32 MB
  unsigned short* qB   = (unsigned short*)alloc((size_t)S_LEN * NHEAD * HD * 2);  // 16 MB
  unsigned short* kB   = (unsigned short*)alloc((size_t)S_LEN * NKVH * HD * 2);   // 4 MB
  unsigned short* vB   = (unsigned short*)alloc((size_t)S_LEN * NKVH * HD * 2);   // 4 MB
  unsigned short* aoB  = (unsigned short*)alloc((size_t)S_LEN * NHEAD * HD * 2);  // 16 MB

  // 1. fp32 -> bf16
  cvt_f32_bf16<<<2048, 256, 0, stream>>>(hs, hidB, S_LEN * HID / 4);
  cvt_f32_bf16<<<2048, 256, 0, stream>>>(Wq, wqB, NHEAD * HD * HID / 4);
  cvt_f32_bf16<<<2048, 256, 0, stream>>>(Wk, wkB, NKVH * HD * HID / 4);
  cvt_f32_bf16<<<2048, 256, 0, stream>>>(Wv, wvB, NKVH * HD * HID / 4);
  cvt_f32_bf16<<<2048, 256, 0, stream>>>(Wo, woB, NHEAD * HD * NHEAD * HD / 4);

  // 2. QKV projections (C = hidden @ W^T)
  gemm_bt<false><<<dim3(NHEAD * HD / 128, S_LEN / 128), 256, 0, stream>>>(
      hidB, wqB, qB, S_LEN, NHEAD * HD, HID);
  gemm_bt<false><<<dim3(NKVH * HD / 128, S_LEN / 128), 256, 0, stream>>>(
      hidB, wkB, kB, S_LEN, NKVH * HD, HID);
  gemm_bt<false><<<dim3(NKVH * HD / 128, S_LEN / 128), 256, 0, stream>>>(
      hidB, wvB, vB, S_LEN, NKVH * HD, HID);

  // 3. RoPE in place
  rope_kernel<<<(S_LEN * NHEAD * 64) / 256, 256, 0, stream>>>(qB, cosp, sinp, 5);
  rope_kernel<<<(S_LEN * NKVH * 64) / 256, 256, 0, stream>>>(kB, cosp, sinp, 3);

  // 4. flash attention
  flash_attn<<<dim3(S_LEN / 64, NHEAD), 256, 0, stream>>>(qB, kB, vB, aoB);

  // 5. output projection, fp32 straight to d_out
  gemm_bt<true><<<dim3(NHEAD * HD / 128, S_LEN / 128), 256, 0, stream>>>(
      aoB, woB, out, S_LEN, NHEAD * HD, NHEAD * HD);
}

// Round 2
// 527.888 us; speedup vs baseline: 1.2170x; 1.2170x over previous
//
#include <hip/hip_runtime.h>
#include <hip/hip_bf16.h>
#include <cstdint>
#include <cstddef>

// Problem constants: B=1, S=2048, H=4096, NH=32, NKV=8, D=128, GQA group=4
#define S_LEN 2048
#define HID   4096
#define NHEAD 32
#define NKVH  8
#define HD    128
#define QKV_STR 6144   // fused qkv row stride (4096 Q + 1024 K + 1024 V)

typedef __bf16 bf16x8 __attribute__((ext_vector_type(8)));
typedef float  f32x4  __attribute__((ext_vector_type(4)));
typedef float  f32x16 __attribute__((ext_vector_type(16)));

__device__ __forceinline__ unsigned short f2bf(float f) {
  union { float f; unsigned int u; } c; c.f = f;
  unsigned int u = c.u;
  return (unsigned short)((u + 0x7fffu + ((u >> 16) & 1u)) >> 16);  // RNE
}
__device__ __forceinline__ void gload16(const void* g, void* l) {
  __builtin_amdgcn_global_load_lds((const __attribute__((address_space(1))) void*)g,
                                   (__attribute__((address_space(3))) void*)l, 16, 0, 0);
}

// ---------------------------------------------------------------- fp32 -> bf16
__global__ void cvt_f32_bf16(const float* __restrict__ in,
                             unsigned short* __restrict__ out, int n4) {
  int i = blockIdx.x * blockDim.x + threadIdx.x;
  int stride = gridDim.x * blockDim.x;
  for (; i < n4; i += stride) {
    float4 v = ((const float4*)in)[i];
    ushort4 o;
    o.x = f2bf(v.x); o.y = f2bf(v.y); o.z = f2bf(v.z); o.w = f2bf(v.w);
    ((ushort4*)out)[i] = o;
  }
}

// ------------------------------------------------- C[M,N] = A[M,K] * B[N,K]^T
// m97 structure: 128x128 tile, BK=32, 4 waves, 4x4 16x16x32 mfma per wave.
template <bool F32OUT>
__global__ __launch_bounds__(256)
void gemm_bt(const unsigned short* __restrict__ A,
             const unsigned short* __restrict__ Bm,
             void* __restrict__ Cout, int M, int N, int K) {
  __shared__ __align__(16) unsigned short lA[128 * 32];
  __shared__ __align__(16) unsigned short lB[128 * 32];
  const int tid = threadIdx.x;
  const int lane = tid & 63, wid = tid >> 6;
  const int l15 = lane & 15, lg = lane >> 4;
  const int wr = (wid >> 1) * 64, wc = (wid & 1) * 64;
  const int bm = blockIdx.y, bn = blockIdx.x;
  f32x4 acc[4][4] = {};
  const unsigned short* Ab = A + (size_t)bm * 128 * K;
  const unsigned short* Bb = Bm + (size_t)bn * 128 * K;

  for (int k0 = 0; k0 < K; k0 += 32) {
#pragma unroll
    for (int i = 0; i < 2; ++i) {     // 512 16B chunks per 8KB tile, 2/thread
      int c = tid + i * 256;
      int row = c >> 2, sl = c & 3;
      gload16(Ab + (size_t)row * K + k0 + sl * 8, (char*)lA + c * 16);
      gload16(Bb + (size_t)row * K + k0 + sl * 8, (char*)lB + c * 16);
    }
    __syncthreads();                  // drains vmcnt -> tiles staged
    bf16x8 af[4], bfr[4];
#pragma unroll
    for (int m = 0; m < 4; ++m)
      af[m] = *(const bf16x8*)&lA[(wr + m * 16 + l15) * 32 + lg * 8];
#pragma unroll
    for (int n = 0; n < 4; ++n)
      bfr[n] = *(const bf16x8*)&lB[(wc + n * 16 + l15) * 32 + lg * 8];
#pragma unroll
    for (int m = 0; m < 4; ++m)
#pragma unroll
      for (int n = 0; n < 4; ++n)
        acc[m][n] = __builtin_amdgcn_mfma_f32_16x16x32_bf16(af[m], bfr[n], acc[m][n], 0, 0, 0);
    __syncthreads();                  // protect LDS before next stage
  }
  // epilogue: C layout col=lane&15, row=4*(lane>>4)+reg
  const int r0 = bm * 128 + wr + 4 * lg;
  const int c0 = bn * 128 + wc + l15;
#pragma unroll
  for (int m = 0; m < 4; ++m)
#pragma unroll
    for (int n = 0; n < 4; ++n)
#pragma unroll
      for (int j = 0; j < 4; ++j) {
        size_t idx = (size_t)(r0 + m * 16 + j) * N + (c0 + n * 16);
        if (F32OUT) ((float*)Cout)[idx] = acc[m][n][j];
        else        ((unsigned short*)Cout)[idx] = f2bf(acc[m][n][j]);
      }
}

// ------------------------------------------------------------- RoPE, in place
// X: base ptr (already offset to first head col); row stride rs;
// cos/sin: [S][128] fp32 (cos[d]==cos[d+64])
__global__ void rope_kernel(unsigned short* __restrict__ X,
                            const float* __restrict__ cp,
                            const float* __restrict__ sp, int lognh, int rs) {
  int idx = blockIdx.x * blockDim.x + threadIdx.x;
  int d = idx & 63;
  int head = (idx >> 6) & ((1 << lognh) - 1);
  int s = idx >> (6 + lognh);
  float c = cp[s * 128 + d], sn = sp[s * 128 + d];
  size_t base = (size_t)s * rs + (head << 7) + d;
  float x1 = __bfloat162float(*(const __hip_bfloat16*)&X[base]);
  float x2 = __bfloat162float(*(const __hip_bfloat16*)&X[base + 64]);
  X[base]      = f2bf(x1 * c - x2 * sn);
  X[base + 64] = f2bf(x2 * c + x1 * sn);
}

// ------------------------------------------------------------ flash attention
// Swapped-QK^T 32x32 structure: grid (16 qtiles, 32 heads), 4 waves x 32 q-rows.
// S^T = mfma32(K-frag, Q-frag): lane owns q = lane&31; softmax lane-local.
// P -> A-frag in-register via bf16 pack + shfl_xor(32).  KVBLK=64, dbuf LDS,
// one barrier per tile.  K: source-swizzled global_load_lds.  V^T: scatter
// with (d^(d>>3))&7 chunk swizzle; B-frag ds_read_b128 conflict-free.
#define CROW(r) (((r) & 3) + 8 * ((r) >> 2) + 4 * hi)
__global__ __launch_bounds__(256, 2)
void flash_attn(const unsigned short* __restrict__ qkv,
                unsigned short* __restrict__ Og) {
  __shared__ __align__(16) unsigned short lK[2 * 64 * 128];
  __shared__ __align__(16) unsigned short lVt[2 * 128 * 64];
  const int tid = threadIdx.x;
  const int lane = tid & 63, w = tid >> 6;
  const int l31 = lane & 31, hi = lane >> 5;
  const int h = blockIdx.y, kvh = h >> 2;
  const int qt = (gridDim.x - 1) - blockIdx.x;       // heavy blocks first
  const int nt = 2 * qt + 2;
  const int qlane = qt * 128 + w * 32 + l31;
  const int qminw = qt * 128 + w * 32;
  const int qmaxw = qminw + 31;
  const float S2 = 0.12752960f;                      // (1/sqrt(128))*log2(e)

  // Q B-fragments, hoisted: lane holds Q[q=l31][ks*16 + hi*8 + j]
  bf16x8 qf[8];
  {
    const unsigned short* qp = qkv + (size_t)qlane * QKV_STR + h * HD + hi * 8;
#pragma unroll
    for (int ks = 0; ks < 8; ++ks) qf[ks] = *(const bf16x8*)(qp + ks * 16);
  }
  f32x16 accO[4] = {};
  float m_run = -3e38f, l_run = 0.f;

  const unsigned short* Kb0 = qkv + 4096 + kvh * HD;
  const unsigned short* Vb0 = qkv + 5120 + kvh * HD;

  auto stageK = [&](int t, int buf) {
    const unsigned short* Kb = Kb0 + (size_t)(t * 64) * QKV_STR;
    unsigned short* dst = lK + buf * (64 * 128);
#pragma unroll
    for (int i = 0; i < 4; ++i) {
      int c = tid + i * 256;
      int row = c >> 4, s = c & 15;
      gload16(Kb + (size_t)row * QKV_STR + (s ^ (row & 7)) * 8, (char*)dst + c * 16);
    }
  };
  auto loadV = [&](int t, uint4* vr) {
    const unsigned short* Vb = Vb0 + (size_t)(t * 64) * QKV_STR;
#pragma unroll
    for (int i = 0; i < 4; ++i) {
      int c = tid + i * 256;
      int row = c >> 4, s = c & 15;
      vr[i] = *(const uint4*)(Vb + (size_t)row * QKV_STR + s * 8);
    }
  };
  auto writeV = [&](const uint4* vr, int buf) {
    unsigned short* dst = lVt + buf * (128 * 64);
#pragma unroll
    for (int i = 0; i < 4; ++i) {
      int c = tid + i * 256;
      int k = c >> 4, s = c & 15;
      const unsigned short* pv = (const unsigned short*)&vr[i];
#pragma unroll
      for (int j = 0; j < 8; ++j) {
        int d = s * 8 + j;
        dst[d * 64 + (k ^ ((((d ^ (d >> 3)) & 7)) << 3))] = pv[j];
      }
    }
  };

  // prologue: stage tile 0
  {
    uint4 vr[4];
    loadV(0, vr);
    stageK(0, 0);
    writeV(vr, 0);
  }
  __syncthreads();

  int cur = 0;
  for (int t = 0; t < nt; ++t) {
    uint4 vr[4];
    const bool pf = (t + 1 < nt);
    if (pf) { loadV(t + 1, vr); stageK(t + 1, cur ^ 1); }

    // ---- compute tile t from buffers[cur] ----
#pragma unroll
    for (int c2 = 0; c2 < 2; ++c2) {
      const int kvb = t * 64 + c2 * 32;
      if (kvb > qmaxw) continue;                     // fully masked (wave-uniform)
      // QK^T: S^T[kv][q], lane q = l31, rows kv = CROW(r)
      f32x16 st = {};
      const unsigned short* lKc = lK + cur * (64 * 128) + c2 * 32 * 128;
#pragma unroll
      for (int ks = 0; ks < 8; ++ks) {
        bf16x8 kf = *(const bf16x8*)&lKc[l31 * 128 + (((ks * 2 + hi) ^ (l31 & 7)) * 8)];
        st = __builtin_amdgcn_mfma_f32_32x32x16_bf16(kf, qf[ks], st, 0, 0, 0);
      }
      if (kvb + 31 > qminw) {                        // diagonal: causal mask
#pragma unroll
        for (int r = 0; r < 16; ++r)
          if (kvb + CROW(r) > qlane) st[r] = -3e38f;
      }
      // online softmax (lane-local over 16 + partner exchange)
      float tm = st[0];
#pragma unroll
      for (int r = 1; r < 16; ++r) tm = fmaxf(tm, st[r]);
      tm = fmaxf(tm, __shfl_xor(tm, 32));
      const bool skip = __all(tm <= m_run);          // defer-max fast path
      float corr = 1.f;
      if (!skip) {
        float mnew = fmaxf(m_run, tm);
        corr = __builtin_amdgcn_exp2f((m_run - mnew) * S2);
        m_run = mnew;
      }
      const float mS2 = m_run * S2;
      float p[16], rsum = 0.f;
#pragma unroll
      for (int r = 0; r < 16; ++r) {
        p[r] = __builtin_amdgcn_exp2f(st[r] * S2 - mS2);
        rsum += p[r];
      }
      rsum += __shfl_xor(rsum, 32);
      l_run = l_run * corr + rsum;
      if (!skip) {
#pragma unroll
        for (int r = 0; r < 16; ++r) {
          float cr = __shfl(corr, CROW(r));
#pragma unroll
          for (int db = 0; db < 4; ++db) accO[db][r] *= cr;
        }
      }
      // pack P -> A-fragments (in-register, T12 structure)
      unsigned wpk[8], xpk[8];
#pragma unroll
      for (int i = 0; i < 8; ++i) {
        __hip_bfloat162 b2 = __float22bfloat162_rn(float2{p[2 * i], p[2 * i + 1]});
        wpk[i] = *(unsigned*)&b2;
        xpk[i] = (unsigned)__shfl_xor((int)wpk[i], 32);
      }
      int4 pa0i, pa1i;
      pa0i.x = hi ? (int)xpk[2] : (int)wpk[0]; pa0i.y = hi ? (int)xpk[3] : (int)wpk[1];
      pa0i.z = hi ? (int)wpk[2] : (int)xpk[0]; pa0i.w = hi ? (int)wpk[3] : (int)xpk[1];
      pa1i.x = hi ? (int)xpk[6] : (int)wpk[4]; pa1i.y = hi ? (int)xpk[7] : (int)wpk[5];
      pa1i.z = hi ? (int)wpk[6] : (int)xpk[4]; pa1i.w = hi ? (int)wpk[7] : (int)xpk[5];
      bf16x8 pa0 = *(bf16x8*)&pa0i, pa1 = *(bf16x8*)&pa1i;
      // PV: accO[db] += P * V
      const unsigned short* lVc = lVt + cur * (128 * 64);
#pragma unroll
      for (int db = 0; db < 4; ++db) {
        int d = db * 32 + l31;
        int swz = (d ^ (d >> 3)) & 7;
#pragma unroll
        for (int ks2 = 0; ks2 < 2; ++ks2) {
          int ck = c2 * 4 + ks2 * 2 + hi;
          bf16x8 vf = *(const bf16x8*)&lVc[d * 64 + ((ck ^ swz) * 8)];
          accO[db] = __builtin_amdgcn_mfma_f32_32x32x16_bf16(ks2 ? pa1 : pa0, vf, accO[db], 0, 0, 0);
        }
      }
    }
    // ---- end compute ----
    if (pf) writeV(vr, cur ^ 1);
    __syncthreads();   // drains vmcnt (K staged) + lgkm (V writes visible)
    cur ^= 1;
  }

  // epilogue: O /= l, bf16 to [s][h*128+d]
  const float invl = 1.0f / l_run;
#pragma unroll
  for (int r = 0; r < 16; ++r) {
    float il = __shfl(invl, CROW(r));
    size_t row = (size_t)(qt * 128 + w * 32 + CROW(r));
#pragma unroll
    for (int db = 0; db < 4; ++db)
      Og[row * (NHEAD * HD) + h * HD + db * 32 + l31] = f2bf(accO[db][r] * il);
  }
}

// ---------------------------------------------------------------------- launch
extern "C" void kernel_launch(void* const* d_in, const int* in_sizes, int n_in,
                              void* d_out, int out_size, void* d_ws, size_t ws_size,
                              hipStream_t stream) {
  const float* hs   = (const float*)d_in[0];
  const float* cosp = (const float*)d_in[1];
  const float* sinp = (const float*)d_in[2];
  // d_in[3] attention_mask: pure causal, implemented directly
  const float* Wq = (const float*)d_in[4];
  const float* Wk = (const float*)d_in[5];
  const float* Wv = (const float*)d_in[6];
  const float* Wo = (const float*)d_in[7];
  float* out = (float*)d_out;

  uint8_t* ws = (uint8_t*)d_ws;
  size_t off = 0;
  auto alloc = [&](size_t bytes) { void* p = ws + off; off += bytes; return p; };
  unsigned short* hidB  = (unsigned short*)alloc((size_t)S_LEN * HID * 2);          // 16 MB
  unsigned short* wqkvB = (unsigned short*)alloc((size_t)QKV_STR * HID * 2);        // 48 MB
  unsigned short* woB   = (unsigned short*)alloc((size_t)HID * HID * 2);            // 32 MB
  unsigned short* qkvB  = (unsigned short*)alloc((size_t)S_LEN * QKV_STR * 2);      // 24 MB
  unsigned short* aoB   = (unsigned short*)alloc((size_t)S_LEN * HID * 2);          // 16 MB

  // 1. fp32 -> bf16 (Wq/Wk/Wv into one concatenated [6144][4096] buffer)
  cvt_f32_bf16<<<2048, 256, 0, stream>>>(hs, hidB, S_LEN * HID / 4);
  cvt_f32_bf16<<<2048, 256, 0, stream>>>(Wq, wqkvB, NHEAD * HD * HID / 4);
  cvt_f32_bf16<<<2048, 256, 0, stream>>>(Wk, wqkvB + (size_t)HID * HID, NKVH * HD * HID / 4);
  cvt_f32_bf16<<<2048, 256, 0, stream>>>(Wv, wqkvB + (size_t)(HID + 1024) * HID, NKVH * HD * HID / 4);
  cvt_f32_bf16<<<2048, 256, 0, stream>>>(Wo, woB, HID * HID / 4);

  // 2. fused QKV projection: [2048][6144] = hid @ WqkvT
  gemm_bt<false><<<dim3(QKV_STR / 128, S_LEN / 128), 256, 0, stream>>>(
      hidB, wqkvB, qkvB, S_LEN, QKV_STR, HID);

  // 3. RoPE in place (Q cols 0..4095, K cols 4096..5119)
  rope_kernel<<<(S_LEN * NHEAD * 64) / 256, 256, 0, stream>>>(qkvB, cosp, sinp, 5, QKV_STR);
  rope_kernel<<<(S_LEN * NKVH * 64) / 256, 256, 0, stream>>>(qkvB + HID, cosp, sinp, 3, QKV_STR);

  // 4. flash attention (swapped 32x32)
  flash_attn<<<dim3(S_LEN / 128, NHEAD), 256, 0, stream>>>(qkvB, aoB);

  // 5. output projection, fp32 straight to d_out
  gemm_bt<true><<<dim3(HID / 128, S_LEN / 128), 256, 0, stream>>>(
      aoB, woB, out, S_LEN, HID, HID);
}

// Round 3
// 416.750 us; speedup vs baseline: 1.5416x; 1.2667x over previous
//
#include <hip/hip_runtime.h>
#include <hip/hip_bf16.h>
#include <cstdint>
#include <cstddef>

// Problem constants: B=1, S=2048, H=4096, NH=32, NKV=8, D=128, GQA group=4
#define S_LEN 2048
#define HID   4096
#define NHEAD 32
#define NKVH  8
#define HD    128
#define QKV_STR 6144   // fused qkv row stride (4096 Q + 1024 K + 1024 V)

typedef __bf16 bf16x8 __attribute__((ext_vector_type(8)));
typedef float  f32x4  __attribute__((ext_vector_type(4)));
typedef float  f32x16 __attribute__((ext_vector_type(16)));

__device__ __forceinline__ unsigned short f2bf(float f) {
  union { float f; unsigned int u; } c; c.f = f;
  unsigned int u = c.u;
  return (unsigned short)((u + 0x7fffu + ((u >> 16) & 1u)) >> 16);  // RNE
}
__device__ __forceinline__ void gload16(const void* g, void* l) {
  __builtin_amdgcn_global_load_lds((const __attribute__((address_space(1))) void*)g,
                                   (__attribute__((address_space(3))) void*)l, 16, 0, 0);
}

// ---------------------------------------------------------------- fp32 -> bf16
__global__ void cvt_f32_bf16(const float* __restrict__ in,
                             unsigned short* __restrict__ out, int n4) {
  int i = blockIdx.x * blockDim.x + threadIdx.x;
  int stride = gridDim.x * blockDim.x;
  for (; i < n4; i += stride) {
    float4 v = ((const float4*)in)[i];
    ushort4 o;
    o.x = f2bf(v.x); o.y = f2bf(v.y); o.z = f2bf(v.z); o.w = f2bf(v.w);
    ((ushort4*)out)[i] = o;
  }
}

// ------------------------------------------------- C[M,N] = A[M,K] * B[N,K]^T
template <bool F32OUT>
__global__ __launch_bounds__(256)
void gemm_bt(const unsigned short* __restrict__ A,
             const unsigned short* __restrict__ Bm,
             void* __restrict__ Cout, int M, int N, int K) {
  __shared__ __align__(16) unsigned short lA[128 * 32];
  __shared__ __align__(16) unsigned short lB[128 * 32];
  const int tid = threadIdx.x;
  const int lane = tid & 63, wid = tid >> 6;
  const int l15 = lane & 15, lg = lane >> 4;
  const int wr = (wid >> 1) * 64, wc = (wid & 1) * 64;
  const int bm = blockIdx.y, bn = blockIdx.x;
  f32x4 acc[4][4] = {};
  const unsigned short* Ab = A + (size_t)bm * 128 * K;
  const unsigned short* Bb = Bm + (size_t)bn * 128 * K;

  for (int k0 = 0; k0 < K; k0 += 32) {
#pragma unroll
    for (int i = 0; i < 2; ++i) {
      int c = tid + i * 256;
      int row = c >> 2, sl = c & 3;
      gload16(Ab + (size_t)row * K + k0 + sl * 8, (char*)lA + c * 16);
      gload16(Bb + (size_t)row * K + k0 + sl * 8, (char*)lB + c * 16);
    }
    __syncthreads();
    bf16x8 af[4], bfr[4];
#pragma unroll
    for (int m = 0; m < 4; ++m)
      af[m] = *(const bf16x8*)&lA[(wr + m * 16 + l15) * 32 + lg * 8];
#pragma unroll
    for (int n = 0; n < 4; ++n)
      bfr[n] = *(const bf16x8*)&lB[(wc + n * 16 + l15) * 32 + lg * 8];
#pragma unroll
    for (int m = 0; m < 4; ++m)
#pragma unroll
      for (int n = 0; n < 4; ++n)
        acc[m][n] = __builtin_amdgcn_mfma_f32_16x16x32_bf16(af[m], bfr[n], acc[m][n], 0, 0, 0);
    __syncthreads();
  }
  const int r0 = bm * 128 + wr + 4 * lg;
  const int c0 = bn * 128 + wc + l15;
#pragma unroll
  for (int m = 0; m < 4; ++m)
#pragma unroll
    for (int n = 0; n < 4; ++n)
#pragma unroll
      for (int j = 0; j < 4; ++j) {
        size_t idx = (size_t)(r0 + m * 16 + j) * N + (c0 + n * 16);
        if (F32OUT) ((float*)Cout)[idx] = acc[m][n][j];
        else        ((unsigned short*)Cout)[idx] = f2bf(acc[m][n][j]);
      }
}

// ------------------------------------------------------------- RoPE, in place
__global__ void rope_kernel(unsigned short* __restrict__ X,
                            const float* __restrict__ cp,
                            const float* __restrict__ sp, int lognh, int rs) {
  int idx = blockIdx.x * blockDim.x + threadIdx.x;
  int d = idx & 63;
  int head = (idx >> 6) & ((1 << lognh) - 1);
  int s = idx >> (6 + lognh);
  float c = cp[s * 128 + d], sn = sp[s * 128 + d];
  size_t base = (size_t)s * rs + (head << 7) + d;
  float x1 = __bfloat162float(*(const __hip_bfloat16*)&X[base]);
  float x2 = __bfloat162float(*(const __hip_bfloat16*)&X[base + 64]);
  X[base]      = f2bf(x1 * c - x2 * sn);
  X[base + 64] = f2bf(x2 * c + x1 * sn);
}

// ----------------------------------------- V transpose: VT[kvh][d][s] (bf16)
// tile transpose with XOR-swizzled LDS columns (chunk ^= (s^(s>>3))&7)
__global__ __launch_bounds__(256)
void transpose_v(const unsigned short* __restrict__ qkv,
                 unsigned short* __restrict__ VT) {
  __shared__ __align__(16) unsigned short tile[128 * 128];
  const int tid = threadIdx.x;
  const int s0 = blockIdx.x * 128;
  const int kvh = blockIdx.y;
  const unsigned short* src = qkv + 5120 + kvh * 128;
#pragma unroll
  for (int i = 0; i < 8; ++i) {
    int c = tid + i * 256;
    int s = c >> 4, dc = c & 15;
    int f = (s ^ (s >> 3)) & 7;
    uint4 v = *(const uint4*)(src + (size_t)(s0 + s) * QKV_STR + dc * 8);
    *(uint4*)&tile[s * 128 + ((dc ^ f) * 8)] = v;
  }
  __syncthreads();
#pragma unroll
  for (int i = 0; i < 8; ++i) {
    int c = tid + i * 256;
    int d = c >> 4, sc = c & 15;
    unsigned short tmp[8];
#pragma unroll
    for (int j = 0; j < 8; ++j) {
      int s = sc * 8 + j;
      int f = (s ^ (s >> 3)) & 7;
      tmp[j] = tile[s * 128 + (((d >> 3) ^ f) * 8) + (d & 7)];
    }
    *(uint4*)(VT + ((size_t)kvh * 128 + d) * S_LEN + s0 + sc * 8) = *(uint4*)tmp;
  }
}

// ------------------------------------------------------------ flash attention
// Swapped-QK^T 32x32: grid (16 qtiles, 32 heads), 4 waves x 32 q-rows.
// st = mfma(K,Q): lane owns q = lane&31 (col); rows = kv.
// accO^T = mfma(V^T, P): rows = d, cols = q  ->  corr / 1/l are LANE-LOCAL.
// K and V^T both staged via source-swizzled global_load_lds (no ds_writes).
#define CROW(r) (((r) & 3) + 8 * ((r) >> 2) + 4 * hi)
__global__ __launch_bounds__(256, 2)
void flash_attn(const unsigned short* __restrict__ qkv,
                const unsigned short* __restrict__ VT,
                unsigned short* __restrict__ Og) {
  __shared__ __align__(16) unsigned short lK[2 * 64 * 128];
  __shared__ __align__(16) unsigned short lVt[2 * 128 * 64];
  const int tid = threadIdx.x;
  const int lane = tid & 63, w = tid >> 6;
  const int l31 = lane & 31, hi = lane >> 5;
  const int h = blockIdx.y, kvh = h >> 2;
  const int qt = (gridDim.x - 1) - blockIdx.x;       // heavy blocks first
  const int nt = 2 * qt + 2;
  const int qlane = qt * 128 + w * 32 + l31;
  const int qmaxw = qt * 128 + w * 32 + 31;
  const float S2 = 0.12752960f;                      // (1/sqrt(128))*log2(e)

  bf16x8 qf[8];
  {
    const unsigned short* qp = qkv + (size_t)qlane * QKV_STR + h * HD + hi * 8;
#pragma unroll
    for (int ks = 0; ks < 8; ++ks) qf[ks] = *(const bf16x8*)(qp + ks * 16);
  }
  f32x16 accO[4] = {};
  float m_run = -3e38f, l_run = 0.f;

  const unsigned short* Kb0 = qkv + 4096 + kvh * HD;
  const unsigned short* VTh = VT + (size_t)kvh * 128 * S_LEN;

  auto stageK = [&](int t, int buf) {
    const unsigned short* Kb = Kb0 + (size_t)(t * 64) * QKV_STR;
    char* dst = (char*)(lK + buf * (64 * 128));
#pragma unroll
    for (int i = 0; i < 4; ++i) {
      int c = tid + i * 256;
      int row = c >> 4, s = c & 15;
      gload16(Kb + (size_t)row * QKV_STR + ((s ^ (row & 7)) * 8), dst + c * 16);
    }
  };
  auto stageV = [&](int t, int buf) {
    const unsigned short* Vb = VTh + t * 64;
    char* dst = (char*)(lVt + buf * (128 * 64));
#pragma unroll
    for (int i = 0; i < 4; ++i) {
      int c = tid + i * 256;
      int d = c >> 3, s = c & 7;
      gload16(Vb + (size_t)d * S_LEN + ((s ^ (d & 7)) * 8), dst + c * 16);
    }
  };

  stageK(0, 0);
  stageV(0, 0);
  __syncthreads();

  int cur = 0;
  for (int t = 0; t < nt; ++t) {
    const bool pf = (t + 1 < nt);
    if (pf) { stageK(t + 1, cur ^ 1); stageV(t + 1, cur ^ 1); }

#pragma unroll
    for (int c2 = 0; c2 < 2; ++c2) {
      const int kvb = t * 64 + c2 * 32;
      if (kvb > qmaxw) continue;                     // fully masked (wave-uniform)
      // QK^T: st[kv][q], lane = q, rows kv = CROW(r)
      f32x16 st = {};
      const unsigned short* lKc = lK + cur * (64 * 128) + c2 * 32 * 128;
#pragma unroll
      for (int ks = 0; ks < 8; ++ks) {
        bf16x8 kf = *(const bf16x8*)&lKc[l31 * 128 + (((ks * 2 + hi) ^ (l31 & 7)) * 8)];
        st = __builtin_amdgcn_mfma_f32_32x32x16_bf16(kf, qf[ks], st, 0, 0, 0);
      }
      if (kvb + 31 > qt * 128 + w * 32) {            // diagonal: causal mask
#pragma unroll
        for (int r = 0; r < 16; ++r)
          if (kvb + CROW(r) > qlane) st[r] = -3e38f;
      }
      // online softmax: lane-local over 16 regs + partner exchange
      float t0 = fmaxf(st[0], st[1]),  t1 = fmaxf(st[2], st[3]);
      float t2 = fmaxf(st[4], st[5]),  t3 = fmaxf(st[6], st[7]);
      float t4 = fmaxf(st[8], st[9]),  t5 = fmaxf(st[10], st[11]);
      float t6 = fmaxf(st[12], st[13]), t7 = fmaxf(st[14], st[15]);
      float tm = fmaxf(fmaxf(fmaxf(t0, t1), fmaxf(t2, t3)),
                       fmaxf(fmaxf(t4, t5), fmaxf(t6, t7)));
      tm = fmaxf(tm, __shfl_xor(tm, 32));
      const bool skip = __all(tm <= m_run);          // no max growth -> no rescale
      float corr = 1.f;
      if (!skip) {
        float mnew = fmaxf(m_run, tm);
        corr = __builtin_amdgcn_exp2f((m_run - mnew) * S2);
        m_run = mnew;
      }
      const float mS2 = m_run * S2;
      float p[16];
#pragma unroll
      for (int r = 0; r < 16; ++r) p[r] = __builtin_amdgcn_exp2f(st[r] * S2 - mS2);
      float s0b = (p[0] + p[1]) + (p[2] + p[3]);
      float s1b = (p[4] + p[5]) + (p[6] + p[7]);
      float s2b = (p[8] + p[9]) + (p[10] + p[11]);
      float s3b = (p[12] + p[13]) + (p[14] + p[15]);
      float rsum = (s0b + s1b) + (s2b + s3b);
      rsum += __shfl_xor(rsum, 32);
      l_run = l_run * corr + rsum;
      if (!skip) {
#pragma unroll
        for (int db = 0; db < 4; ++db) accO[db] = accO[db] * corr;   // lane-local
      }
      // pack P -> B-fragments (in-register)
      unsigned wpk[8], xpk[8];
#pragma unroll
      for (int i = 0; i < 8; ++i) {
        __hip_bfloat162 b2 = __float22bfloat162_rn(float2{p[2 * i], p[2 * i + 1]});
        wpk[i] = *(unsigned*)&b2;
        xpk[i] = (unsigned)__shfl_xor((int)wpk[i], 32);
      }
      int4 pa0i, pa1i;
      pa0i.x = hi ? (int)xpk[2] : (int)wpk[0]; pa0i.y = hi ? (int)xpk[3] : (int)wpk[1];
      pa0i.z = hi ? (int)wpk[2] : (int)xpk[0]; pa0i.w = hi ? (int)wpk[3] : (int)xpk[1];
      pa1i.x = hi ? (int)xpk[6] : (int)wpk[4]; pa1i.y = hi ? (int)xpk[7] : (int)wpk[5];
      pa1i.z = hi ? (int)wpk[6] : (int)xpk[4]; pa1i.w = hi ? (int)wpk[7] : (int)xpk[5];
      bf16x8 pa0 = *(bf16x8*)&pa0i, pa1 = *(bf16x8*)&pa1i;
      // PV: accO^T[d][q] += V^T[d][kv] * P[kv][q]
      const unsigned short* lVc = lVt + cur * (128 * 64);
#pragma unroll
      for (int db = 0; db < 4; ++db) {
        int d = db * 32 + l31;
#pragma unroll
        for (int ks2 = 0; ks2 < 2; ++ks2) {
          int ck = c2 * 4 + ks2 * 2 + hi;
          bf16x8 vf = *(const bf16x8*)&lVc[d * 64 + ((ck ^ (d & 7)) * 8)];
          accO[db] = __builtin_amdgcn_mfma_f32_32x32x16_bf16(vf, ks2 ? pa1 : pa0, accO[db], 0, 0, 0);
        }
      }
    }
    __syncthreads();   // drains vmcnt: next tile fully staged
    cur ^= 1;
  }

  // epilogue: lane owns column q; invl lane-local; packed 8B stores
  const float invl = 1.0f / l_run;
  unsigned short* orow = Og + (size_t)(qt * 128 + w * 32 + l31) * HID + h * HD;
#pragma unroll
  for (int db = 0; db < 4; ++db)
#pragma unroll
    for (int rr = 0; rr < 4; ++rr) {
      int d0 = db * 32 + rr * 8 + 4 * hi;
      ushort4 o;
      o.x = f2bf(accO[db][rr * 4 + 0] * invl);
      o.y = f2bf(accO[db][rr * 4 + 1] * invl);
      o.z = f2bf(accO[db][rr * 4 + 2] * invl);
      o.w = f2bf(accO[db][rr * 4 + 3] * invl);
      *(ushort4*)(orow + d0) = o;
    }
}

// ---------------------------------------------------------------------- launch
extern "C" void kernel_launch(void* const* d_in, const int* in_sizes, int n_in,
                              void* d_out, int out_size, void* d_ws, size_t ws_size,
                              hipStream_t stream) {
  const float* hs   = (const float*)d_in[0];
  const float* cosp = (const float*)d_in[1];
  const float* sinp = (const float*)d_in[2];
  const float* Wq = (const float*)d_in[4];
  const float* Wk = (const float*)d_in[5];
  const float* Wv = (const float*)d_in[6];
  const float* Wo = (const float*)d_in[7];
  float* out = (float*)d_out;

  uint8_t* ws = (uint8_t*)d_ws;
  size_t off = 0;
  auto alloc = [&](size_t bytes) { void* p = ws + off; off += bytes; return p; };
  unsigned short* hidB  = (unsigned short*)alloc((size_t)S_LEN * HID * 2);
  unsigned short* wqkvB = (unsigned short*)alloc((size_t)QKV_STR * HID * 2);
  unsigned short* woB   = (unsigned short*)alloc((size_t)HID * HID * 2);
  unsigned short* qkvB  = (unsigned short*)alloc((size_t)S_LEN * QKV_STR * 2);
  unsigned short* aoB   = (unsigned short*)alloc((size_t)S_LEN * HID * 2);
  unsigned short* vtB   = (unsigned short*)alloc((size_t)NKVH * HD * S_LEN * 2);

  cvt_f32_bf16<<<2048, 256, 0, stream>>>(hs, hidB, S_LEN * HID / 4);
  cvt_f32_bf16<<<2048, 256, 0, stream>>>(Wq, wqkvB, NHEAD * HD * HID / 4);
  cvt_f32_bf16<<<2048, 256, 0, stream>>>(Wk, wqkvB + (size_t)HID * HID, NKVH * HD * HID / 4);
  cvt_f32_bf16<<<2048, 256, 0, stream>>>(Wv, wqkvB + (size_t)(HID + 1024) * HID, NKVH * HD * HID / 4);
  cvt_f32_bf16<<<2048, 256, 0, stream>>>(Wo, woB, HID * HID / 4);

  gemm_bt<false><<<dim3(QKV_STR / 128, S_LEN / 128), 256, 0, stream>>>(
      hidB, wqkvB, qkvB, S_LEN, QKV_STR, HID);

  rope_kernel<<<(S_LEN * NHEAD * 64) / 256, 256, 0, stream>>>(qkvB, cosp, sinp, 5, QKV_STR);
  rope_kernel<<<(S_LEN * NKVH * 64) / 256, 256, 0, stream>>>(qkvB + HID, cosp, sinp, 3, QKV_STR);

  transpose_v<<<dim3(S_LEN / 128, NKVH), 256, 0, stream>>>(qkvB, vtB);

  flash_attn<<<dim3(S_LEN / 128, NHEAD), 256, 0, stream>>>(qkvB, vtB, aoB);

  gemm_bt<true><<<dim3(HID / 128, S_LEN / 128), 256, 0, stream>>>(
      aoB, woB, out, S_LEN, HID, HID);
}

// Round 5
// 367.431 us; speedup vs baseline: 1.7485x; 1.1342x over previous
//
#include <hip/hip_runtime.h>
#include <hip/hip_bf16.h>
#include <cstdint>
#include <cstddef>

// Problem constants: B=1, S=2048, H=4096, NH=32, NKV=8, D=128, GQA group=4
#define S_LEN 2048
#define HID   4096
#define NHEAD 32
#define NKVH  8
#define HD    128
#define QKV_STR 6144   // fused qkv row stride (4096 Q + 1024 K + 1024 V)

typedef __bf16 bf16x8 __attribute__((ext_vector_type(8)));
typedef float  f32x4  __attribute__((ext_vector_type(4)));
typedef float  f32x16 __attribute__((ext_vector_type(16)));

__device__ __forceinline__ unsigned short f2bf(float f) {
  union { float f; unsigned int u; } c; c.f = f;
  unsigned int u = c.u;
  return (unsigned short)((u + 0x7fffu + ((u >> 16) & 1u)) >> 16);  // RNE
}
__device__ __forceinline__ void gload16(const void* g, void* l) {
  __builtin_amdgcn_global_load_lds((const __attribute__((address_space(1))) void*)g,
                                   (__attribute__((address_space(3))) void*)l, 16, 0, 0);
}

// ------------------------------------------- fp32 -> bf16, 5 segments, 1 launch
__global__ void cvt_multi(const float* __restrict__ s0, const float* __restrict__ s1,
                          const float* __restrict__ s2, const float* __restrict__ s3,
                          const float* __restrict__ s4,
                          unsigned short* __restrict__ d0, unsigned short* __restrict__ d1,
                          unsigned short* __restrict__ d2, unsigned short* __restrict__ d3,
                          unsigned short* __restrict__ d4,
                          int n0, int n1, int n2, int n3, int n4c) {
  const float* src; unsigned short* dst; int n;
  switch (blockIdx.y) {
    case 0: src = s0; dst = d0; n = n0; break;
    case 1: src = s1; dst = d1; n = n1; break;
    case 2: src = s2; dst = d2; n = n2; break;
    case 3: src = s3; dst = d3; n = n3; break;
    default: src = s4; dst = d4; n = n4c; break;
  }
  int i = blockIdx.x * blockDim.x + threadIdx.x;
  int stride = gridDim.x * blockDim.x;
  for (; i < n; i += stride) {
    float4 v = ((const float4*)src)[i];
    ushort4 o;
    o.x = f2bf(v.x); o.y = f2bf(v.y); o.z = f2bf(v.z); o.w = f2bf(v.w);
    ((ushort4*)dst)[i] = o;
  }
}

// ------------------------------------------------- C[M,N] = A[M,K] * B[N,K]^T
// 128x128 tile, BK=32, 4 waves, triple-buffered LDS with counted vmcnt:
// per K-step {vmcnt(4); barrier; issue stage(t+2); ds_read(t); 16 MFMA} —
// stage(t+1) stays in flight across the barrier (T3/T4).  LDS chunk swizzle
// chunk^=(row>>1)&3 via pre-swizzled global source (rule #21) kills the 8-way
// frag-read conflict.  M hard-coded 2048 (16 block-rows).  XCD-aware swizzle,
// bm-fastest so each XCD chunk reuses few B (weight) panels in its L2.
template <bool F32OUT>
__global__ __launch_bounds__(256)
void gemm_bt(const unsigned short* __restrict__ A,
             const unsigned short* __restrict__ Bm,
             void* __restrict__ Cout, int N, int K) {
  __shared__ __align__(16) unsigned short lA[3][128 * 32];
  __shared__ __align__(16) unsigned short lB[3][128 * 32];
  const int tid = threadIdx.x;
  const int lane = tid & 63, wid = tid >> 6;
  const int l15 = lane & 15, lg = lane >> 4;
  const int wr = (wid >> 1) * 64, wc = (wid & 1) * 64;
  // XCD swizzle (nwg % 8 == 0 for both call sites), bm-fastest
  const int nwg = gridDim.x * 16;
  int bid = blockIdx.x + blockIdx.y * gridDim.x;
  bid = (bid & 7) * (nwg >> 3) + (bid >> 3);
  const int bm = bid & 15, bn = bid >> 4;

  f32x4 acc[4][4] = {};
  const unsigned short* Ab = A + (size_t)bm * 128 * K;
  const unsigned short* Bb = Bm + (size_t)bn * 128 * K;

  auto stage = [&](int t, int buf) {
    const int k0 = t * 32;
#pragma unroll
    for (int i = 0; i < 2; ++i) {     // 4 gloads/thread per tile (2 A + 2 B)
      int c = tid + i * 256;
      int row = c >> 2, sl = c & 3;
      int g = sl ^ ((row >> 1) & 3);  // inverse chunk swizzle on source
      gload16(Ab + (size_t)row * K + k0 + g * 8, (char*)lA[buf] + c * 16);
      gload16(Bb + (size_t)row * K + k0 + g * 8, (char*)lB[buf] + c * 16);
    }
  };

  const int nt = K / 32;
  stage(0, 0);
  if (nt > 1) stage(1, 1);
  const int swz = (l15 >> 1) & 3;     // read-side chunk swizzle (lane-constant)

  int cur = 0;
  for (int t = 0; t < nt; ++t) {
    if (t + 1 < nt) asm volatile("s_waitcnt vmcnt(4)" ::: "memory");
    else            asm volatile("s_waitcnt vmcnt(0)" ::: "memory");
    __builtin_amdgcn_s_barrier();
    __builtin_amdgcn_sched_barrier(0);
    if (t + 2 < nt) { int nb = cur + 2; if (nb >= 3) nb -= 3; stage(t + 2, nb); }
    bf16x8 af[4], bfr[4];
#pragma unroll
    for (int m = 0; m < 4; ++m)
      af[m] = *(const bf16x8*)&lA[cur][(wr + m * 16 + l15) * 32 + ((lg ^ swz) * 8)];
#pragma unroll
    for (int n = 0; n < 4; ++n)
      bfr[n] = *(const bf16x8*)&lB[cur][(wc + n * 16 + l15) * 32 + ((lg ^ swz) * 8)];
#pragma unroll
    for (int m = 0; m < 4; ++m)
#pragma unroll
      for (int n = 0; n < 4; ++n)
        acc[m][n] = __builtin_amdgcn_mfma_f32_16x16x32_bf16(af[m], bfr[n], acc[m][n], 0, 0, 0);
    ++cur; if (cur >= 3) cur -= 3;
  }
  // epilogue: C layout col=lane&15, row=4*(lane>>4)+reg
  const int r0 = bm * 128 + wr + 4 * lg;
  const int c0 = bn * 128 + wc + l15;
#pragma unroll
  for (int m = 0; m < 4; ++m)
#pragma unroll
    for (int n = 0; n < 4; ++n)
#pragma unroll
      for (int j = 0; j < 4; ++j) {
        size_t idx = (size_t)(r0 + m * 16 + j) * N + (c0 + n * 16);
        if (F32OUT) ((float*)Cout)[idx] = acc[m][n][j];
        else        ((unsigned short*)Cout)[idx] = f2bf(acc[m][n][j]);
      }
}

// ------------------------------------------------------------- RoPE, in place
__global__ void rope_kernel(unsigned short* __restrict__ X,
                            const float* __restrict__ cp,
                            const float* __restrict__ sp, int lognh, int rs) {
  int idx = blockIdx.x * blockDim.x + threadIdx.x;
  int d = idx & 63;
  int head = (idx >> 6) & ((1 << lognh) - 1);
  int s = idx >> (6 + lognh);
  float c = cp[s * 128 + d], sn = sp[s * 128 + d];
  size_t base = (size_t)s * rs + (head << 7) + d;
  float x1 = __bfloat162float(*(const __hip_bfloat16*)&X[base]);
  float x2 = __bfloat162float(*(const __hip_bfloat16*)&X[base + 64]);
  X[base]      = f2bf(x1 * c - x2 * sn);
  X[base + 64] = f2bf(x2 * c + x1 * sn);
}

// ----------------------------------------- V transpose: VT[kvh][d][s] (bf16)
__global__ __launch_bounds__(256)
void transpose_v(const unsigned short* __restrict__ qkv,
                 unsigned short* __restrict__ VT) {
  __shared__ __align__(16) unsigned short tile[128 * 128];
  const int tid = threadIdx.x;
  const int s0 = blockIdx.x * 128;
  const int kvh = blockIdx.y;
  const unsigned short* src = qkv + 5120 + kvh * 128;
#pragma unroll
  for (int i = 0; i < 8; ++i) {
    int c = tid + i * 256;
    int s = c >> 4, dc = c & 15;
    int f = (s ^ (s >> 3)) & 7;
    uint4 v = *(const uint4*)(src + (size_t)(s0 + s) * QKV_STR + dc * 8);
    *(uint4*)&tile[s * 128 + ((dc ^ f) * 8)] = v;
  }
  __syncthreads();
#pragma unroll
  for (int i = 0; i < 8; ++i) {
    int c = tid + i * 256;
    int d = c >> 4, sc = c & 15;
    unsigned short tmp[8];
#pragma unroll
    for (int j = 0; j < 8; ++j) {
      int s = sc * 8 + j;
      int f = (s ^ (s >> 3)) & 7;
      tmp[j] = tile[s * 128 + (((d >> 3) ^ f) * 8) + (d & 7)];
    }
    *(uint4*)(VT + ((size_t)kvh * 128 + d) * S_LEN + s0 + sc * 8) = *(uint4*)tmp;
  }
}

// ------------------------------------------------------------ flash attention
// Swapped-QK^T 32x32: grid (16 qtiles, 32 heads), 4 waves x 32 q-rows.
// st = mfma(K,Q): lane owns q = lane&31 (col); rows = kv.
// accO^T = mfma(V^T, P): rows = d, cols = q  ->  corr / 1/l are LANE-LOCAL.
// K and V^T both staged via source-swizzled global_load_lds (no ds_writes).
#define CROW(r) (((r) & 3) + 8 * ((r) >> 2) + 4 * hi)
__global__ __launch_bounds__(256, 2)
void flash_attn(const unsigned short* __restrict__ qkv,
                const unsigned short* __restrict__ VT,
                unsigned short* __restrict__ Og) {
  __shared__ __align__(16) unsigned short lK[2 * 64 * 128];
  __shared__ __align__(16) unsigned short lVt[2 * 128 * 64];
  const int tid = threadIdx.x;
  const int lane = tid & 63, w = tid >> 6;
  const int l31 = lane & 31, hi = lane >> 5;
  const int h = blockIdx.y, kvh = h >> 2;
  const int qt = (gridDim.x - 1) - blockIdx.x;       // heavy blocks first
  const int nt = 2 * qt + 2;
  const int qlane = qt * 128 + w * 32 + l31;
  const int qmaxw = qt * 128 + w * 32 + 31;
  const float S2 = 0.12752960f;                      // (1/sqrt(128))*log2(e)

  bf16x8 qf[8];
  {
    const unsigned short* qp = qkv + (size_t)qlane * QKV_STR + h * HD + hi * 8;
#pragma unroll
    for (int ks = 0; ks < 8; ++ks) qf[ks] = *(const bf16x8*)(qp + ks * 16);
  }
  f32x16 accO[4] = {};
  float m_run = -3e38f, l_run = 0.f;

  const unsigned short* Kb0 = qkv + 4096 + kvh * HD;
  const unsigned short* VTh = VT + (size_t)kvh * 128 * S_LEN;

  auto stageK = [&](int t, int buf) {
    const unsigned short* Kb = Kb0 + (size_t)(t * 64) * QKV_STR;
    char* dst = (char*)(lK + buf * (64 * 128));
#pragma unroll
    for (int i = 0; i < 4; ++i) {
      int c = tid + i * 256;
      int row = c >> 4, s = c & 15;
      gload16(Kb + (size_t)row * QKV_STR + ((s ^ (row & 7)) * 8), dst + c * 16);
    }
  };
  auto stageV = [&](int t, int buf) {
    const unsigned short* Vb = VTh + t * 64;
    char* dst = (char*)(lVt + buf * (128 * 64));
#pragma unroll
    for (int i = 0; i < 4; ++i) {
      int c = tid + i * 256;
      int d = c >> 3, s = c & 7;
      gload16(Vb + (size_t)d * S_LEN + ((s ^ (d & 7)) * 8), dst + c * 16);
    }
  };

  stageK(0, 0);
  stageV(0, 0);
  __syncthreads();

  int cur = 0;
  for (int t = 0; t < nt; ++t) {
    const bool pf = (t + 1 < nt);
    if (pf) { stageK(t + 1, cur ^ 1); stageV(t + 1, cur ^ 1); }

#pragma unroll
    for (int c2 = 0; c2 < 2; ++c2) {
      const int kvb = t * 64 + c2 * 32;
      if (kvb > qmaxw) continue;                     // fully masked (wave-uniform)
      // QK^T: st[kv][q], lane = q, rows kv = CROW(r)
      f32x16 st = {};
      const unsigned short* lKc = lK + cur * (64 * 128) + c2 * 32 * 128;
      __builtin_amdgcn_s_setprio(1);
#pragma unroll
      for (int ks = 0; ks < 8; ++ks) {
        bf16x8 kf = *(const bf16x8*)&lKc[l31 * 128 + (((ks * 2 + hi) ^ (l31 & 7)) * 8)];
        st = __builtin_amdgcn_mfma_f32_32x32x16_bf16(kf, qf[ks], st, 0, 0, 0);
      }
      __builtin_amdgcn_s_setprio(0);
      if (kvb + 31 > qt * 128 + w * 32) {            // diagonal: causal mask
#pragma unroll
        for (int r = 0; r < 16; ++r)
          if (kvb + CROW(r) > qlane) st[r] = -3e38f;
      }
      // online softmax: lane-local over 16 regs + partner exchange
      float t0 = fmaxf(st[0], st[1]),  t1 = fmaxf(st[2], st[3]);
      float t2 = fmaxf(st[4], st[5]),  t3 = fmaxf(st[6], st[7]);
      float t4 = fmaxf(st[8], st[9]),  t5 = fmaxf(st[10], st[11]);
      float t6 = fmaxf(st[12], st[13]), t7 = fmaxf(st[14], st[15]);
      float tm = fmaxf(fmaxf(fmaxf(t0, t1), fmaxf(t2, t3)),
                       fmaxf(fmaxf(t4, t5), fmaxf(t6, t7)));
      tm = fmaxf(tm, __shfl_xor(tm, 32));
      const bool skip = __all(tm <= m_run);          // no max growth -> no rescale
      float corr = 1.f;
      if (!skip) {
        float mnew = fmaxf(m_run, tm);
        corr = __builtin_amdgcn_exp2f((m_run - mnew) * S2);
        m_run = mnew;
      }
      const float mS2 = m_run * S2;
      float p[16];
#pragma unroll
      for (int r = 0; r < 16; ++r) p[r] = __builtin_amdgcn_exp2f(st[r] * S2 - mS2);
      float s0b = (p[0] + p[1]) + (p[2] + p[3]);
      float s1b = (p[4] + p[5]) + (p[6] + p[7]);
      float s2b = (p[8] + p[9]) + (p[10] + p[11]);
      float s3b = (p[12] + p[13]) + (p[14] + p[15]);
      float rsum = (s0b + s1b) + (s2b + s3b);
      rsum += __shfl_xor(rsum, 32);
      l_run = l_run * corr + rsum;
      if (!skip) {
#pragma unroll
        for (int db = 0; db < 4; ++db) accO[db] = accO[db] * corr;   // lane-local
      }
      // pack P -> B-fragments (in-register)
      unsigned wpk[8], xpk[8];
#pragma unroll
      for (int i = 0; i < 8; ++i) {
        __hip_bfloat162 b2 = __float22bfloat162_rn(float2{p[2 * i], p[2 * i + 1]});
        wpk[i] = *(unsigned*)&b2;
        xpk[i] = (unsigned)__shfl_xor((int)wpk[i], 32);
      }
      int4 pa0i, pa1i;
      pa0i.x = hi ? (int)xpk[2] : (int)wpk[0]; pa0i.y = hi ? (int)xpk[3] : (int)wpk[1];
      pa0i.z = hi ? (int)wpk[2] : (int)xpk[0]; pa0i.w = hi ? (int)wpk[3] : (int)xpk[1];
      pa1i.x = hi ? (int)xpk[6] : (int)wpk[4]; pa1i.y = hi ? (int)xpk[7] : (int)wpk[5];
      pa1i.z = hi ? (int)wpk[6] : (int)xpk[4]; pa1i.w = hi ? (int)wpk[7] : (int)xpk[5];
      bf16x8 pa0 = *(bf16x8*)&pa0i, pa1 = *(bf16x8*)&pa1i;
      // PV: accO^T[d][q] += V^T[d][kv] * P[kv][q]
      const unsigned short* lVc = lVt + cur * (128 * 64);
      __builtin_amdgcn_s_setprio(1);
#pragma unroll
      for (int db = 0; db < 4; ++db) {
        int d = db * 32 + l31;
#pragma unroll
        for (int ks2 = 0; ks2 < 2; ++ks2) {
          int ck = c2 * 4 + ks2 * 2 + hi;
          bf16x8 vf = *(const bf16x8*)&lVc[d * 64 + ((ck ^ (d & 7)) * 8)];
          accO[db] = __builtin_amdgcn_mfma_f32_32x32x16_bf16(vf, ks2 ? pa1 : pa0, accO[db], 0, 0, 0);
        }
      }
      __builtin_amdgcn_s_setprio(0);
    }
    __syncthreads();   // drains vmcnt: next tile fully staged
    cur ^= 1;
  }

  // epilogue: lane owns column q; invl lane-local; packed 8B stores
  const float invl = 1.0f / l_run;
  unsigned short* orow = Og + (size_t)(qt * 128 + w * 32 + l31) * HID + h * HD;
#pragma unroll
  for (int db = 0; db < 4; ++db)
#pragma unroll
    for (int rr = 0; rr < 4; ++rr) {
      int d0 = db * 32 + rr * 8 + 4 * hi;
      ushort4 o;
      o.x = f2bf(accO[db][rr * 4 + 0] * invl);
      o.y = f2bf(accO[db][rr * 4 + 1] * invl);
      o.z = f2bf(accO[db][rr * 4 + 2] * invl);
      o.w = f2bf(accO[db][rr * 4 + 3] * invl);
      *(ushort4*)(orow + d0) = o;
    }
}

// ---------------------------------------------------------------------- launch
extern "C" void kernel_launch(void* const* d_in, const int* in_sizes, int n_in,
                              void* d_out, int out_size, void* d_ws, size_t ws_size,
                              hipStream_t stream) {
  const float* hs   = (const float*)d_in[0];
  const float* cosp = (const float*)d_in[1];
  const float* sinp = (const float*)d_in[2];
  const float* Wq = (const float*)d_in[4];
  const float* Wk = (const float*)d_in[5];
  const float* Wv = (const float*)d_in[6];
  const float* Wo = (const float*)d_in[7];
  float* out = (float*)d_out;

  uint8_t* ws = (uint8_t*)d_ws;
  size_t off = 0;
  auto alloc = [&](size_t bytes) { void* p = ws + off; off += bytes; return p; };
  unsigned short* hidB  = (unsigned short*)alloc((size_t)S_LEN * HID * 2);
  unsigned short* wqkvB = (unsigned short*)alloc((size_t)QKV_STR * HID * 2);
  unsigned short* woB   = (unsigned short*)alloc((size_t)HID * HID * 2);
  unsigned short* qkvB  = (unsigned short*)alloc((size_t)S_LEN * QKV_STR * 2);
  unsigned short* aoB   = (unsigned short*)alloc((size_t)S_LEN * HID * 2);
  unsigned short* vtB   = (unsigned short*)alloc((size_t)NKVH * HD * S_LEN * 2);

  // 1. fp32 -> bf16, all five tensors in one launch
  cvt_multi<<<dim3(1024, 5), 256, 0, stream>>>(
      hs, Wq, Wk, Wv, Wo,
      hidB, wqkvB, wqkvB + (size_t)HID * HID, wqkvB + (size_t)(HID + 1024) * HID, woB,
      S_LEN * HID / 4, HID * HID / 4, 1024 * HID / 4, 1024 * HID / 4, HID * HID / 4);

  // 2. fused QKV projection: [2048][6144] = hid @ WqkvT
  gemm_bt<false><<<dim3(QKV_STR / 128, S_LEN / 128), 256, 0, stream>>>(
      hidB, wqkvB, qkvB, QKV_STR, HID);

  // 3. RoPE in place (Q cols 0..4095, K cols 4096..5119)
  rope_kernel<<<(S_LEN * NHEAD * 64) / 256, 256, 0, stream>>>(qkvB, cosp, sinp, 5, QKV_STR);
  rope_kernel<<<(S_LEN * NKVH * 64) / 256, 256, 0, stream>>>(qkvB + HID, cosp, sinp, 3, QKV_STR);

  // 4. V transpose for conflict-free PV staging
  transpose_v<<<dim3(S_LEN / 128, NKVH), 256, 0, stream>>>(qkvB, vtB);

  // 5. flash attention (swapped 32x32)
  flash_attn<<<dim3(S_LEN / 128, NHEAD), 256, 0, stream>>>(qkvB, vtB, aoB);

  // 6. output projection, fp32 straight to d_out  (N = HID — the R4 bug)
  gemm_bt<true><<<dim3(HID / 128, S_LEN / 128), 256, 0, stream>>>(
      aoB, woB, out, HID, HID);
}